// Round 8
// baseline (362.904 us; speedup 1.0000x reference)
//
#include <hip/hip_runtime.h>
#include <hip/hip_bf16.h>
#include <math.h>

#define B_   4
#define C_   192
#define N_   6400
#define K_   9
#define M_   50
#define TK_  12
#define OC_  192
#define KC_  576     // 3*C
#define CH_  200     // 32-point chunks per batch
#define PC_  32      // points per chunk
#define LSTR 53      // padded lg row stride (fp32; odd -> conflict-free)
#define BSTR 36      // x-tile LDS row stride
#define GSTR 40      // bf16 LDS row stride (80 B, 16B-aligned, 2-way -> free)

typedef __bf16 b16x8 __attribute__((ext_vector_type(8)));
typedef float f32x4 __attribute__((ext_vector_type(4)));

__device__ inline unsigned short f2b(float f) {
    union { __hip_bfloat16 h; unsigned short u; } v;
    v.h = __float2bfloat16(f);
    return v.u;
}
__device__ inline float b2f(unsigned short u) {
    union { float f; unsigned int i; } v;
    v.i = ((unsigned int)u) << 16;
    return v.f;
}

// ---------------- W re-permute -> bf16: Wg16[o][t*192+ch] = conv_w[o][ch*3+t]
__global__ void k_rearrange_w(const float* __restrict__ cw, unsigned short* __restrict__ Wg16) {
    int g = blockIdx.x * 256 + threadIdx.x;           // < 192*576
    int o = g / KC_, r = g % KC_;
    int t = r / C_, ch = r % C_;
    Wg16[g] = f2b(cw[o * KC_ + ch * 3 + t]);
}

// ---------------- transpose x (b,c,n) -> xt fp32 + xt16 bf16 (b,n,c) ---------
__global__ void k_transpose(const float* __restrict__ x, float* __restrict__ xt,
                            unsigned short* __restrict__ xt16) {
    __shared__ float tile[32][33];
    int b = blockIdx.z;
    int p0 = blockIdx.x * 32, c0 = blockIdx.y * 32;
    int tx = threadIdx.x, ty = threadIdx.y;
    const float* xb = x + (size_t)b * C_ * N_;
    float* xtb = xt + (size_t)b * N_ * C_;
    unsigned short* xt16b = xt16 + (size_t)b * N_ * C_;
#pragma unroll
    for (int i = 0; i < 4; i++) {
        int cc = ty + 8 * i;
        tile[cc][tx] = xb[(size_t)(c0 + cc) * N_ + p0 + tx];
    }
    __syncthreads();
#pragma unroll
    for (int i = 0; i < 4; i++) {
        int pp = ty + 8 * i;
        float v = tile[tx][pp];
        size_t o = (size_t)(p0 + pp) * C_ + c0 + tx;
        xtb[o] = v;
        xt16b[o] = f2b(v);
    }
}

// ------- initial centroids: 5x10 adaptive avg pool (+ |c|^2, + acc zero) -----
__global__ __launch_bounds__(192) void k_init_cent(const float* __restrict__ xt,
        float* __restrict__ cent, float* __restrict__ c2,
        float* __restrict__ centacc, float* __restrict__ wsum) {
    int m = blockIdx.x, b = blockIdx.y, c = threadIdx.x;
    int gy = m / 10, gx = m % 10;
    const float* xtb = xt + (size_t)b * N_ * C_;
    float s = 0.f;
    for (int yy = 0; yy < 16; yy++)
        for (int xx = 0; xx < 8; xx++) {
            int p = (gy * 16 + yy) * 80 + gx * 8 + xx;
            s += xtb[(size_t)p * C_ + c];
        }
    float v = s * (1.f / 128.f);
    size_t o = ((size_t)b * M_ + m) * C_ + c;
    cent[o] = v;
    centacc[o] = 0.f;                        // zero atomic accumulator
    if (c == 0) wsum[(size_t)b * M_ + m] = 0.f;
    float q = v * v;
    __shared__ float red[3];
#pragma unroll
    for (int off = 32; off > 0; off >>= 1) q += __shfl_down(q, off, 64);
    if ((c & 63) == 0) red[c >> 6] = q;
    __syncthreads();
    if (c == 0) c2[(size_t)b * M_ + m] = red[0] + red[1] + red[2];
}

// ==== fused: logits GEMM + softmax + atomic partial accumulation (+ topk) ====
// block = 32 points. phase 1: lg[p][m] = softmax_m(2*x.c - |c|^2)
// phase 2: centacc[m][c] += sum_p lg[p][m]*x[p][c] (fp32 atomics, L2-resident)
__global__ __launch_bounds__(256) void k_logits_upd(const float* __restrict__ xt,
        const float* __restrict__ cent, const float* __restrict__ c2g,
        float* __restrict__ centacc, float* __restrict__ wsum,
        int* __restrict__ nn, int do_topk) {
    __shared__ float Ac[16][68];
    __shared__ float Bp[16][BSTR];
    __shared__ float lg[PC_ * LSTR];
    __shared__ float sred[256];
    int b = blockIdx.y;
    int blk = blockIdx.x;
    int p0 = blk * PC_;
    int tid = threadIdx.x;
    int tx = tid & 15, ty = tid >> 4;
    int lr = tid >> 2, lq = tid & 3;
    const float* cb = cent + (size_t)b * M_ * C_;
    const float* xb = xt + ((size_t)b * N_ + p0) * C_;
    // ---- phase 1: logits GEMM (32 p x 50 m, K=192) ----
    {
        float acc[4][2];
#pragma unroll
        for (int i = 0; i < 4; i++) { acc[i][0] = 0.f; acc[i][1] = 0.f; }
        for (int kt = 0; kt < 12; kt++) {
            int kg = kt * 16;
            float4 cv = make_float4(0.f, 0.f, 0.f, 0.f);
            if (lr < M_) cv = *(const float4*)&cb[(size_t)lr * C_ + kg + 4 * lq];
            float4 pv = make_float4(0.f, 0.f, 0.f, 0.f);
            if (tid < 128) pv = *(const float4*)&xb[(size_t)(tid >> 2) * C_ + kg + 4 * lq];
            __syncthreads();
            Ac[4 * lq + 0][lr] = cv.x; Ac[4 * lq + 1][lr] = cv.y;
            Ac[4 * lq + 2][lr] = cv.z; Ac[4 * lq + 3][lr] = cv.w;
            if (tid < 128) {
                int xr = tid >> 2;
                Bp[4 * lq + 0][xr] = pv.x; Bp[4 * lq + 1][xr] = pv.y;
                Bp[4 * lq + 2][xr] = pv.z; Bp[4 * lq + 3][xr] = pv.w;
            }
            __syncthreads();
#pragma unroll
            for (int kk = 0; kk < 16; kk++) {
                float4 a = *(const float4*)&Ac[kk][4 * ty];
                float2 bb = *(const float2*)&Bp[kk][2 * tx];
                acc[0][0] += a.x * bb.x; acc[0][1] += a.x * bb.y;
                acc[1][0] += a.y * bb.x; acc[1][1] += a.y * bb.y;
                acc[2][0] += a.z * bb.x; acc[2][1] += a.z * bb.y;
                acc[3][0] += a.w * bb.x; acc[3][1] += a.w * bb.y;
            }
        }
#pragma unroll
        for (int i = 0; i < 4; i++) {
            int m = 4 * ty + i;
            if (m < M_) {
                float c2v = c2g[(size_t)b * M_ + m];
                lg[(2 * tx + 0) * LSTR + m] = 2.f * acc[i][0] - c2v;
                lg[(2 * tx + 1) * LSTR + m] = 2.f * acc[i][1] - c2v;
            }
        }
    }
    __syncthreads();
    // ---- softmax (8-way parallel per row) ----
    {
        int p = tid & 31, prt = tid >> 5;
        int m0 = prt * 6;
        int m1 = (prt == 7) ? M_ : m0 + 6;
        float* row = &lg[p * LSTR];
        float mx = -1e30f;
        for (int m = m0; m < m1; m++) mx = fmaxf(mx, row[m]);
        sred[prt * 32 + p] = mx;
        __syncthreads();
        mx = sred[p];
#pragma unroll
        for (int k = 1; k < 8; k++) mx = fmaxf(mx, sred[k * 32 + p]);
        float s = 0.f;
        for (int m = m0; m < m1; m++) {
            float e = expf(row[m] - mx);
            row[m] = e;
            s += e;
        }
        __syncthreads();
        sred[prt * 32 + p] = s;
        __syncthreads();
        s = sred[p];
#pragma unroll
        for (int k = 1; k < 8; k++) s += sred[k * 32 + p];
        float inv = 1.f / s;
        for (int m = m0; m < m1; m++) row[m] *= inv;
    }
    __syncthreads();
    // ---- phase 2: atomic partials (lg read-only from here) ----
    if (tid < 192) {
        int c = tid;
        float acc[M_];
#pragma unroll
        for (int mm = 0; mm < M_; mm++) acc[mm] = 0.f;
#pragma unroll
        for (int pc = 0; pc < 2; pc++) {
            float xq[16];
#pragma unroll
            for (int i = 0; i < 16; i++)
                xq[i] = xb[(size_t)(pc * 16 + i) * C_ + c];   // independent L2-hot loads
#pragma unroll
            for (int i = 0; i < 16; i++) {
                const float* row = &lg[(pc * 16 + i) * LSTR];
#pragma unroll
                for (int mm = 0; mm < M_; mm++)
                    acc[mm] += row[mm] * xq[i];               // broadcast ds_reads
            }
        }
        float* ab = centacc + (size_t)b * M_ * C_;
#pragma unroll
        for (int mm = 0; mm < M_; mm++)
            atomicAdd(&ab[(size_t)mm * C_ + c], acc[mm]);     // coalesced per-wave
    } else if (tid < 192 + M_) {
        int m = tid - 192;
        float s = 0.f;
        for (int p = 0; p < PC_; p++) s += lg[p * LSTR + m];
        atomicAdd(&wsum[(size_t)b * M_ + m], s);
    }
    // ---- topk on last iteration (destroys lg; after phase-2 reads) ----
    if (do_topk) {
        __syncthreads();
        if (tid < PC_) {
            float* row = &lg[tid * LSTR];
            int* nb = nn + ((size_t)b * N_ + p0 + tid) * TK_;
            for (int r = 0; r < TK_; r++) {
                float bv = -1.f;
                int bi = 0;
                for (int m = 0; m < M_; m++) {
                    float v = row[m];
                    if (v > bv) { bv = v; bi = m; }   // strict > : lowest index wins ties
                }
                nb[r] = bi;
                row[bi] = -1.f;
            }
        }
    }
}

// ---- normalize centroids from atomic accumulators; zero them for next iter --
__global__ __launch_bounds__(192) void k_cent_norm(float* __restrict__ centacc,
        float* __restrict__ wsum, float* __restrict__ cent, float* __restrict__ c2,
        unsigned short* __restrict__ cent16, int last) {
    int m = blockIdx.x, b = blockIdx.y, c = threadIdx.x;
    __shared__ float sws;
    __shared__ float red[3];
    if (c == 0) sws = wsum[(size_t)b * M_ + m] + 1e-8f;
    __syncthreads();
    size_t o = ((size_t)b * M_ + m) * C_ + c;
    float v = centacc[o] / sws;
    centacc[o] = 0.f;                         // reset for next iteration
    cent[o] = v;
    if (last) cent16[o] = f2b(v);
    if (c == 0) wsum[(size_t)b * M_ + m] = 0.f;
    float q = v * v;
#pragma unroll
    for (int off = 32; off > 0; off >>= 1) q += __shfl_down(q, off, 64);
    if ((c & 63) == 0) red[c >> 6] = q;
    __syncthreads();
    if (c == 0) c2[(size_t)b * M_ + m] = red[0] + red[1] + red[2];
}

// ---------------- gathers (bf16 sources): edge max-rel + topk-centroid max ---
__global__ __launch_bounds__(192) void k_gather(const unsigned short* __restrict__ xt16,
        const unsigned short* __restrict__ cent16, const int* __restrict__ edge,
        const int* __restrict__ nn, unsigned short* __restrict__ xjt16,
        unsigned short* __restrict__ xjct16) {
    __shared__ int sidx[2 * K_ + TK_];
    int p = blockIdx.x, b = blockIdx.y, c = threadIdx.x;
    if (c < K_)
        sidx[c] = edge[((size_t)b * N_ + p) * K_ + c];
    else if (c < 2 * K_)
        sidx[c] = edge[(size_t)B_ * N_ * K_ + ((size_t)b * N_ + p) * K_ + (c - K_)];
    else if (c < 2 * K_ + TK_)
        sidx[c] = nn[((size_t)b * N_ + p) * TK_ + (c - 2 * K_)];
    __syncthreads();
    const unsigned short* xb = xt16 + (size_t)b * N_ * C_;
    const unsigned short* cbv = cent16 + (size_t)b * M_ * C_;
    float xv = b2f(xb[(size_t)p * C_ + c]);
    float mj = -1e30f;
#pragma unroll
    for (int kk = 0; kk < K_; kk++) {
        float vj = b2f(xb[(size_t)sidx[kk] * C_ + c]);
        float vi = b2f(xb[(size_t)sidx[K_ + kk] * C_ + c]);
        mj = fmaxf(mj, vj - vi);
    }
    float mc = -1e30f;
#pragma unroll
    for (int kk = 0; kk < TK_; kk++)
        mc = fmaxf(mc, b2f(cbv[(size_t)sidx[2 * K_ + kk] * C_ + c]));
    size_t o = ((size_t)b * N_ + p) * C_ + c;
    xjt16[o] = f2b(mj);
    xjct16[o] = f2b(mc - xv);
}

// ------- final conv via bf16 MFMA: full-OC 192(o) x 64(p) tile, feat read once
__global__ __launch_bounds__(256) void k_gemm(const unsigned short* __restrict__ Wg16,
        const unsigned short* __restrict__ xt16, const unsigned short* __restrict__ xjt16,
        const unsigned short* __restrict__ xjct16, const float* __restrict__ bias,
        float* __restrict__ out) {
    __shared__ short As[192 * GSTR];   // Wg k-chunk [o][32k]
    __shared__ short Bs[64 * GSTR];    // feat k-chunk [p][32k]
    int b = blockIdx.y;
    int po = blockIdx.x * 64;
    int tid = threadIdx.x;
    int wave = tid >> 6, lane = tid & 63;
    int m16 = lane & 15, q = lane >> 4;
    const unsigned short* s0 = xt16 + (size_t)b * N_ * C_;
    const unsigned short* s1 = xjt16 + (size_t)b * N_ * C_;
    const unsigned short* s2 = xjct16 + (size_t)b * N_ * C_;
    f32x4 acc[12];
#pragma unroll
    for (int i = 0; i < 12; i++) acc[i] = (f32x4){0.f, 0.f, 0.f, 0.f};
    int brow = tid >> 2, bch = tid & 3;
    for (int kt = 0; kt < 18; kt++) {
        int kg = kt * 32;
        int prt = kg / C_, koff = kg - prt * C_;
        const unsigned short* src = (prt == 0) ? s0 : ((prt == 1) ? s1 : s2);
        int4 av[3];
#pragma unroll
        for (int t = 0; t < 3; t++) {
            int idx = t * 256 + tid;
            av[t] = *(const int4*)&Wg16[(size_t)(idx >> 2) * KC_ + kg + (idx & 3) * 8];
        }
        int4 bv = *(const int4*)&src[(size_t)(po + brow) * C_ + koff + bch * 8];
        __syncthreads();
#pragma unroll
        for (int t = 0; t < 3; t++) {
            int idx = t * 256 + tid;
            *(int4*)&As[(idx >> 2) * GSTR + (idx & 3) * 8] = av[t];
        }
        *(int4*)&Bs[brow * GSTR + bch * 8] = bv;
        __syncthreads();
        b16x8 bf = *(const b16x8*)&Bs[(wave * 16 + m16) * GSTR + q * 8];
#pragma unroll
        for (int of = 0; of < 12; of++) {
            b16x8 af = *(const b16x8*)&As[(of * 16 + m16) * GSTR + q * 8];
            acc[of] = __builtin_amdgcn_mfma_f32_16x16x32_bf16(af, bf, acc[of], 0, 0, 0);
        }
    }
    int p = po + wave * 16 + m16;
#pragma unroll
    for (int of = 0; of < 12; of++) {
        int o = of * 16 + q * 4;
        float4 bv = *(const float4*)&bias[o];
        float bia[4] = {bv.x, bv.y, bv.z, bv.w};
#pragma unroll
        for (int r = 0; r < 4; r++)
            out[((size_t)b * OC_ + o + r) * N_ + p] = fmaxf(acc[of][r] + bia[r], 0.f);
    }
}

extern "C" void kernel_launch(void* const* d_in, const int* in_sizes, int n_in,
                              void* d_out, int out_size, void* d_ws, size_t ws_size,
                              hipStream_t stream) {
    (void)in_sizes; (void)n_in; (void)out_size; (void)ws_size;
    const float* x   = (const float*)d_in[0];
    const int* edge  = (const int*)d_in[1];
    const float* cw  = (const float*)d_in[2];
    const float* cbi = (const float*)d_in[3];
    float* ws = (float*)d_ws;
    size_t o = 0;
    float* xt   = ws + o; o += (size_t)B_ * N_ * C_;
    unsigned short* xt16 = (unsigned short*)(ws + o); o += (size_t)B_ * N_ * C_ / 2;
    unsigned short* Wg16 = (unsigned short*)(ws + o); o += (size_t)OC_ * KC_ / 2;
    float* cent = ws + o; o += (size_t)B_ * M_ * C_;
    unsigned short* cent16 = (unsigned short*)(ws + o); o += (size_t)B_ * M_ * C_ / 2;
    float* c2   = ws + o; o += (size_t)B_ * M_;
    float* centacc = ws + o; o += (size_t)B_ * M_ * C_;
    float* wsum = ws + o; o += (size_t)B_ * M_;
    int* nn = (int*)(ws + o); o += (size_t)B_ * N_ * TK_;
    unsigned short* xjt16  = (unsigned short*)(ws + o); o += (size_t)B_ * N_ * C_ / 2;
    unsigned short* xjct16 = (unsigned short*)(ws + o); o += (size_t)B_ * N_ * C_ / 2;
    float* outp = (float*)d_out;

    k_rearrange_w<<<dim3(432), dim3(256), 0, stream>>>(cw, Wg16);
    k_transpose<<<dim3(N_ / 32, C_ / 32, B_), dim3(32, 8), 0, stream>>>(x, xt, xt16);
    k_init_cent<<<dim3(M_, B_), dim3(192), 0, stream>>>(xt, cent, c2, centacc, wsum);
    for (int it = 0; it < 3; it++) {
        k_logits_upd<<<dim3(CH_, B_), dim3(256), 0, stream>>>(xt, cent, c2, centacc, wsum, nn, (it == 2) ? 1 : 0);
        k_cent_norm<<<dim3(M_, B_), dim3(192), 0, stream>>>(centacc, wsum, cent, c2, cent16, (it == 2) ? 1 : 0);
    }
    k_gather<<<dim3(N_, B_), dim3(192), 0, stream>>>(xt16, cent16, edge, nn, xjt16, xjct16);
    k_gemm<<<dim3(N_ / 64, B_), dim3(256), 0, stream>>>(Wg16, xt16, xjt16, xjct16, cbi, outp);
}

// Round 9
// 316.668 us; speedup vs baseline: 1.1460x; 1.1460x over previous
//
#include <hip/hip_runtime.h>
#include <hip/hip_bf16.h>
#include <math.h>

#define B_   4
#define C_   192
#define N_   6400
#define K_   9
#define M_   50
#define TK_  12
#define OC_  192
#define KC_  576     // 3*C
#define CH_  100     // 64-point chunks per batch
#define LSTR 53      // padded lg row stride (fp32; odd -> conflict-free)
#define TSTR 72      // lgT row stride (bf16), 144 B, 16B-aligned
#define XSTR 40      // xT row stride (bf16), 80 B, 16B-aligned
#define GSTR 40      // k_gemm bf16 LDS row stride

typedef __bf16 b16x8 __attribute__((ext_vector_type(8)));
typedef float f32x4 __attribute__((ext_vector_type(4)));

__device__ inline unsigned short f2b(float f) {
    union { __hip_bfloat16 h; unsigned short u; } v;
    v.h = __float2bfloat16(f);
    return v.u;
}
__device__ inline float b2f(unsigned short u) {
    union { float f; unsigned int i; } v;
    v.i = ((unsigned int)u) << 16;
    return v.f;
}

// ---------------- W re-permute -> bf16: Wg16[o][t*192+ch] = conv_w[o][ch*3+t]
__global__ void k_rearrange_w(const float* __restrict__ cw, unsigned short* __restrict__ Wg16) {
    int g = blockIdx.x * 256 + threadIdx.x;           // < 192*576
    int o = g / KC_, r = g % KC_;
    int t = r / C_, ch = r % C_;
    Wg16[g] = f2b(cw[o * KC_ + ch * 3 + t]);
}

// ---------------- transpose x (b,c,n) -> xt fp32 + xt16 bf16 (b,n,c) ---------
__global__ void k_transpose(const float* __restrict__ x, float* __restrict__ xt,
                            unsigned short* __restrict__ xt16) {
    __shared__ float tile[32][33];
    int b = blockIdx.z;
    int p0 = blockIdx.x * 32, c0 = blockIdx.y * 32;
    int tx = threadIdx.x, ty = threadIdx.y;
    const float* xb = x + (size_t)b * C_ * N_;
    float* xtb = xt + (size_t)b * N_ * C_;
    unsigned short* xt16b = xt16 + (size_t)b * N_ * C_;
#pragma unroll
    for (int i = 0; i < 4; i++) {
        int cc = ty + 8 * i;
        tile[cc][tx] = xb[(size_t)(c0 + cc) * N_ + p0 + tx];
    }
    __syncthreads();
#pragma unroll
    for (int i = 0; i < 4; i++) {
        int pp = ty + 8 * i;
        float v = tile[tx][pp];
        size_t o = (size_t)(p0 + pp) * C_ + c0 + tx;
        xtb[o] = v;
        xt16b[o] = f2b(v);
    }
}

// ---------------- initial centroids: 5x10 adaptive avg pool (+ |c|^2) --------
__global__ __launch_bounds__(192) void k_init_cent(const float* __restrict__ xt,
        float* __restrict__ cent, float* __restrict__ c2) {
    int m = blockIdx.x, b = blockIdx.y, c = threadIdx.x;
    int gy = m / 10, gx = m % 10;
    const float* xtb = xt + (size_t)b * N_ * C_;
    float s = 0.f;
    for (int yy = 0; yy < 16; yy++)
        for (int xx = 0; xx < 8; xx++) {
            int p = (gy * 16 + yy) * 80 + gx * 8 + xx;
            s += xtb[(size_t)p * C_ + c];
        }
    float v = s * (1.f / 128.f);
    cent[((size_t)b * M_ + m) * C_ + c] = v;
    float q = v * v;
    __shared__ float red[3];
#pragma unroll
    for (int off = 32; off > 0; off >>= 1) q += __shfl_down(q, off, 64);
    if ((c & 63) == 0) red[c >> 6] = q;
    __syncthreads();
    if (c == 0) c2[(size_t)b * M_ + m] = red[0] + red[1] + red[2];
}

// ==== fused: fp32 logits GEMM + softmax + bf16-split MFMA partials (+ topk) ==
// LDS aliasing (52 KB buffer):
//   [0 .. 13568)           lg fp32 [64][LSTR]        (phase 1 / softmax / topk)
//   [13568 .. 22272)       Ac,Bp fp32 [16][68]       (phase-1 staging)
//   [0 .. 33280)           xTh,xTl bf16 [208][XSTR]  (phase 2; lg/Ac/Bp dead)
//   [33280 .. 51712)       lgTh,lgTl bf16 [64][TSTR]
__global__ __launch_bounds__(256) void k_logits_upd(const float* __restrict__ xt,
        const float* __restrict__ cent, const float* __restrict__ c2g,
        float* __restrict__ part, float* __restrict__ wsp,
        int* __restrict__ nn, int do_topk) {
    __shared__ alignas(16) char smem[51712];
    __shared__ float sred[256];
    float* lg = (float*)smem;
    float* Ac = (float*)(smem + 13568);
    float* Bp = (float*)(smem + 17920);
    unsigned short* xTh = (unsigned short*)smem;
    unsigned short* xTl = (unsigned short*)(smem + 16640);
    unsigned short* lgTh = (unsigned short*)(smem + 33280);
    unsigned short* lgTl = (unsigned short*)(smem + 42496);
    int b = blockIdx.y;
    int blk = blockIdx.x;
    int p0 = blk * 64;
    int tid = threadIdx.x;
    int tx = tid & 15, ty = tid >> 4;
    int lr = tid >> 2, lq = tid & 3;
    int wave = tid >> 6, lane = tid & 63;
    int m16 = lane & 15, q = lane >> 4;
    const float* cb = cent + (size_t)b * M_ * C_;
    const float* xb = xt + ((size_t)b * N_ + p0) * C_;
    // ---- phase 1: fp32 logits GEMM (64 p x 50 m, K=192) ----
    {
        float acc[4][4];
#pragma unroll
        for (int i = 0; i < 4; i++)
#pragma unroll
            for (int j = 0; j < 4; j++) acc[i][j] = 0.f;
        for (int kt = 0; kt < 12; kt++) {
            int kg = kt * 16;
            float4 cv = make_float4(0.f, 0.f, 0.f, 0.f);
            if (lr < M_) cv = *(const float4*)&cb[(size_t)lr * C_ + kg + 4 * lq];
            float4 pv = *(const float4*)&xb[(size_t)lr * C_ + kg + 4 * lq];
            __syncthreads();
            Ac[(4 * lq + 0) * 68 + lr] = cv.x; Ac[(4 * lq + 1) * 68 + lr] = cv.y;
            Ac[(4 * lq + 2) * 68 + lr] = cv.z; Ac[(4 * lq + 3) * 68 + lr] = cv.w;
            Bp[(4 * lq + 0) * 68 + lr] = pv.x; Bp[(4 * lq + 1) * 68 + lr] = pv.y;
            Bp[(4 * lq + 2) * 68 + lr] = pv.z; Bp[(4 * lq + 3) * 68 + lr] = pv.w;
            __syncthreads();
#pragma unroll
            for (int kk = 0; kk < 16; kk++) {
                float4 a = *(const float4*)&Ac[kk * 68 + 4 * ty];
                float4 bb = *(const float4*)&Bp[kk * 68 + 4 * tx];
                acc[0][0] += a.x * bb.x; acc[0][1] += a.x * bb.y; acc[0][2] += a.x * bb.z; acc[0][3] += a.x * bb.w;
                acc[1][0] += a.y * bb.x; acc[1][1] += a.y * bb.y; acc[1][2] += a.y * bb.z; acc[1][3] += a.y * bb.w;
                acc[2][0] += a.z * bb.x; acc[2][1] += a.z * bb.y; acc[2][2] += a.z * bb.z; acc[2][3] += a.z * bb.w;
                acc[3][0] += a.w * bb.x; acc[3][1] += a.w * bb.y; acc[3][2] += a.w * bb.z; acc[3][3] += a.w * bb.w;
            }
        }
#pragma unroll
        for (int i = 0; i < 4; i++) {
            int m = 4 * ty + i;
            if (m < M_) {
                float c2v = c2g[(size_t)b * M_ + m];
#pragma unroll
                for (int j = 0; j < 4; j++)
                    lg[(4 * tx + j) * LSTR + m] = 2.f * acc[i][j] - c2v;
            }
        }
    }
    __syncthreads();
    // ---- softmax (4-way parallel per row) ----
    {
        int p = tid & 63, prt = tid >> 6;
        int m0 = prt * 13;
        int m1 = (prt == 3) ? M_ : m0 + 13;
        float* row = &lg[p * LSTR];
        float mx = -1e30f;
        for (int m = m0; m < m1; m++) mx = fmaxf(mx, row[m]);
        sred[prt * 64 + p] = mx;
        __syncthreads();
        mx = fmaxf(fmaxf(sred[p], sred[64 + p]), fmaxf(sred[128 + p], sred[192 + p]));
        float s = 0.f;
        for (int m = m0; m < m1; m++) {
            float e = expf(row[m] - mx);
            row[m] = e;
            s += e;
        }
        __syncthreads();
        sred[prt * 64 + p] = s;
        __syncthreads();
        s = sred[p] + sred[64 + p] + sred[128 + p] + sred[192 + p];
        float inv = 1.f / s;
        for (int m = m0; m < m1; m++) row[m] *= inv;
    }
    __syncthreads();
    // ---- build lgT[m][p] hi/lo bf16 (reads lg stride-1) ----
    for (int j = tid; j < 64 * 64; j += 256) {
        int p = j >> 6, m = j & 63;
        float w = (m < M_) ? lg[p * LSTR + m] : 0.f;
        unsigned short hi = f2b(w);
        lgTh[m * TSTR + p] = hi;
        lgTl[m * TSTR + p] = f2b(w - b2f(hi));
    }
    __syncthreads();
    // ---- topk on last iteration (reads+destroys lg; before xT overwrites) ---
    if (do_topk && tid < 64) {
        float* row = &lg[tid * LSTR];
        int* nb = nn + ((size_t)b * N_ + p0 + tid) * TK_;
        for (int r = 0; r < TK_; r++) {
            float bv = -1.f;
            int bi = 0;
            for (int m = 0; m < M_; m++) {
                float v = row[m];
                if (v > bv) { bv = v; bi = m; }   // strict > : lowest index wins ties
            }
            nb[r] = bi;
            row[bi] = -1.f;
        }
    }
    // ---- phase 2: part[m][c] = sum_p w*x via 3-term bf16-split MFMA ----
    f32x4 acc2[13];
#pragma unroll
    for (int i = 0; i < 13; i++) acc2[i] = (f32x4){0.f, 0.f, 0.f, 0.f};
    for (int h = 0; h < 2; h++) {
        __syncthreads();   // lg/topk done (h=0); prev MFMA reads done (h=1)
        for (int j = tid; j < 32 * C_; j += 256) {
            int pl = j / C_, c = j - pl * C_;
            float v = xb[(size_t)(h * 32 + pl) * C_ + c];
            unsigned short hi = f2b(v);
            xTh[c * XSTR + pl] = hi;
            xTl[c * XSTR + pl] = f2b(v - b2f(hi));
        }
        for (int j = tid; j < 32 * 16; j += 256) {
            int pl = j & 31, c = C_ + (j >> 5);
            xTh[c * XSTR + pl] = (c == C_) ? f2b(1.f) : 0;
            xTl[c * XSTR + pl] = 0;
        }
        __syncthreads();
        b16x8 ah = *(const b16x8*)&lgTh[(wave * 16 + m16) * TSTR + h * 32 + q * 8];
        b16x8 al = *(const b16x8*)&lgTl[(wave * 16 + m16) * TSTR + h * 32 + q * 8];
#pragma unroll
        for (int ct = 0; ct < 13; ct++) {
            b16x8 bh = *(const b16x8*)&xTh[(ct * 16 + m16) * XSTR + q * 8];
            b16x8 bl = *(const b16x8*)&xTl[(ct * 16 + m16) * XSTR + q * 8];
            acc2[ct] = __builtin_amdgcn_mfma_f32_16x16x32_bf16(ah, bh, acc2[ct], 0, 0, 0);
            acc2[ct] = __builtin_amdgcn_mfma_f32_16x16x32_bf16(ah, bl, acc2[ct], 0, 0, 0);
            acc2[ct] = __builtin_amdgcn_mfma_f32_16x16x32_bf16(al, bh, acc2[ct], 0, 0, 0);
        }
    }
    // ---- epilogue: D row m = wave*16 + q*4 + r, col c = ct*16 + m16 ----
    float* pb = part + ((size_t)b * CH_ + blk) * (size_t)(M_ * C_);
    int mbase = wave * 16 + q * 4;
#pragma unroll
    for (int ct = 0; ct < 13; ct++) {
        int c = ct * 16 + m16;
#pragma unroll
        for (int r = 0; r < 4; r++) {
            int mm = mbase + r;
            if (mm >= M_) continue;
            float v = acc2[ct][r];
            if (c < C_) pb[(size_t)mm * C_ + c] = v;
            else if (c == C_) wsp[((size_t)b * CH_ + blk) * M_ + mm] = v;
        }
    }
}

__global__ __launch_bounds__(192) void k_upd_reduce(const float* __restrict__ part,
        const float* __restrict__ wsp, float* __restrict__ cent, float* __restrict__ c2,
        unsigned short* __restrict__ cent16, int last) {
    int m = blockIdx.x, b = blockIdx.y, c = threadIdx.x;
    __shared__ float sws;
    __shared__ float red[3];
    if (c == 0) {
        float s = 0.f;
        for (int ch = 0; ch < CH_; ch++) s += wsp[((size_t)b * CH_ + ch) * M_ + m];
        sws = s + 1e-8f;
    }
    float s = 0.f;
    for (int ch = 0; ch < CH_; ch++)
        s += part[(((size_t)b * CH_ + ch) * M_ + m) * (size_t)C_ + c];
    __syncthreads();
    float v = s / sws;
    size_t o = ((size_t)b * M_ + m) * C_ + c;
    cent[o] = v;
    if (last) cent16[o] = f2b(v);
    float q = v * v;
#pragma unroll
    for (int off = 32; off > 0; off >>= 1) q += __shfl_down(q, off, 64);
    if ((c & 63) == 0) red[c >> 6] = q;
    __syncthreads();
    if (c == 0) c2[(size_t)b * M_ + m] = red[0] + red[1] + red[2];
}

// ---------------- gathers (bf16 sources): edge max-rel + topk-centroid max ---
__global__ __launch_bounds__(192) void k_gather(const unsigned short* __restrict__ xt16,
        const unsigned short* __restrict__ cent16, const int* __restrict__ edge,
        const int* __restrict__ nn, unsigned short* __restrict__ xjt16,
        unsigned short* __restrict__ xjct16) {
    __shared__ int sidx[2 * K_ + TK_];
    int p = blockIdx.x, b = blockIdx.y, c = threadIdx.x;
    if (c < K_)
        sidx[c] = edge[((size_t)b * N_ + p) * K_ + c];
    else if (c < 2 * K_)
        sidx[c] = edge[(size_t)B_ * N_ * K_ + ((size_t)b * N_ + p) * K_ + (c - K_)];
    else if (c < 2 * K_ + TK_)
        sidx[c] = nn[((size_t)b * N_ + p) * TK_ + (c - 2 * K_)];
    __syncthreads();
    const unsigned short* xb = xt16 + (size_t)b * N_ * C_;
    const unsigned short* cbv = cent16 + (size_t)b * M_ * C_;
    float xv = b2f(xb[(size_t)p * C_ + c]);
    float mj = -1e30f;
#pragma unroll
    for (int kk = 0; kk < K_; kk++) {
        float vj = b2f(xb[(size_t)sidx[kk] * C_ + c]);
        float vi = b2f(xb[(size_t)sidx[K_ + kk] * C_ + c]);
        mj = fmaxf(mj, vj - vi);
    }
    float mc = -1e30f;
#pragma unroll
    for (int kk = 0; kk < TK_; kk++)
        mc = fmaxf(mc, b2f(cbv[(size_t)sidx[2 * K_ + kk] * C_ + c]));
    size_t o = ((size_t)b * N_ + p) * C_ + c;
    xjt16[o] = f2b(mj);
    xjct16[o] = f2b(mc - xv);
}

// ------- final conv via bf16 MFMA: full-OC 192(o) x 64(p) tile, feat read once
__global__ __launch_bounds__(256) void k_gemm(const unsigned short* __restrict__ Wg16,
        const unsigned short* __restrict__ xt16, const unsigned short* __restrict__ xjt16,
        const unsigned short* __restrict__ xjct16, const float* __restrict__ bias,
        float* __restrict__ out) {
    __shared__ short As[192 * GSTR];   // Wg k-chunk [o][32k]
    __shared__ short Bs[64 * GSTR];    // feat k-chunk [p][32k]
    int b = blockIdx.y;
    int po = blockIdx.x * 64;
    int tid = threadIdx.x;
    int wave = tid >> 6, lane = tid & 63;
    int m16 = lane & 15, q = lane >> 4;
    const unsigned short* s0 = xt16 + (size_t)b * N_ * C_;
    const unsigned short* s1 = xjt16 + (size_t)b * N_ * C_;
    const unsigned short* s2 = xjct16 + (size_t)b * N_ * C_;
    f32x4 acc[12];
#pragma unroll
    for (int i = 0; i < 12; i++) acc[i] = (f32x4){0.f, 0.f, 0.f, 0.f};
    int brow = tid >> 2, bch = tid & 3;
    for (int kt = 0; kt < 18; kt++) {
        int kg = kt * 32;
        int prt = kg / C_, koff = kg - prt * C_;
        const unsigned short* src = (prt == 0) ? s0 : ((prt == 1) ? s1 : s2);
        int4 av[3];
#pragma unroll
        for (int t = 0; t < 3; t++) {
            int idx = t * 256 + tid;
            av[t] = *(const int4*)&Wg16[(size_t)(idx >> 2) * KC_ + kg + (idx & 3) * 8];
        }
        int4 bv = *(const int4*)&src[(size_t)(po + brow) * C_ + koff + bch * 8];
        __syncthreads();
#pragma unroll
        for (int t = 0; t < 3; t++) {
            int idx = t * 256 + tid;
            *(int4*)&As[(idx >> 2) * GSTR + (idx & 3) * 8] = av[t];
        }
        *(int4*)&Bs[brow * GSTR + bch * 8] = bv;
        __syncthreads();
        b16x8 bf = *(const b16x8*)&Bs[(wave * 16 + m16) * GSTR + q * 8];
#pragma unroll
        for (int of = 0; of < 12; of++) {
            b16x8 af = *(const b16x8*)&As[(of * 16 + m16) * GSTR + q * 8];
            acc[of] = __builtin_amdgcn_mfma_f32_16x16x32_bf16(af, bf, acc[of], 0, 0, 0);
        }
    }
    int p = po + wave * 16 + m16;
#pragma unroll
    for (int of = 0; of < 12; of++) {
        int o = of * 16 + q * 4;
        float4 bv = *(const float4*)&bias[o];
        float bia[4] = {bv.x, bv.y, bv.z, bv.w};
#pragma unroll
        for (int r = 0; r < 4; r++)
            out[((size_t)b * OC_ + o + r) * N_ + p] = fmaxf(acc[of][r] + bia[r], 0.f);
    }
}

extern "C" void kernel_launch(void* const* d_in, const int* in_sizes, int n_in,
                              void* d_out, int out_size, void* d_ws, size_t ws_size,
                              hipStream_t stream) {
    (void)in_sizes; (void)n_in; (void)out_size; (void)ws_size;
    const float* x   = (const float*)d_in[0];
    const int* edge  = (const int*)d_in[1];
    const float* cw  = (const float*)d_in[2];
    const float* cbi = (const float*)d_in[3];
    float* ws = (float*)d_ws;
    size_t o = 0;
    float* xt   = ws + o; o += (size_t)B_ * N_ * C_;
    unsigned short* xt16 = (unsigned short*)(ws + o); o += (size_t)B_ * N_ * C_ / 2;
    unsigned short* Wg16 = (unsigned short*)(ws + o); o += (size_t)OC_ * KC_ / 2;
    float* cent = ws + o; o += (size_t)B_ * M_ * C_;
    unsigned short* cent16 = (unsigned short*)(ws + o); o += (size_t)B_ * M_ * C_ / 2;
    float* c2   = ws + o; o += (size_t)B_ * M_;
    float* part = ws + o; o += (size_t)B_ * CH_ * M_ * C_;
    float* wsp  = ws + o; o += (size_t)B_ * CH_ * M_;
    int* nn = (int*)(ws + o); o += (size_t)B_ * N_ * TK_;
    unsigned short* xjt16  = (unsigned short*)(ws + o); o += (size_t)B_ * N_ * C_ / 2;
    unsigned short* xjct16 = (unsigned short*)(ws + o); o += (size_t)B_ * N_ * C_ / 2;
    float* outp = (float*)d_out;

    k_rearrange_w<<<dim3(432), dim3(256), 0, stream>>>(cw, Wg16);
    k_transpose<<<dim3(N_ / 32, C_ / 32, B_), dim3(32, 8), 0, stream>>>(x, xt, xt16);
    k_init_cent<<<dim3(M_, B_), dim3(192), 0, stream>>>(xt, cent, c2);
    for (int it = 0; it < 3; it++) {
        k_logits_upd<<<dim3(CH_, B_), dim3(256), 0, stream>>>(xt, cent, c2, part, wsp, nn, (it == 2) ? 1 : 0);
        k_upd_reduce<<<dim3(M_, B_), dim3(192), 0, stream>>>(part, wsp, cent, c2, cent16, (it == 2) ? 1 : 0);
    }
    k_gather<<<dim3(N_, B_), dim3(192), 0, stream>>>(xt16, cent16, edge, nn, xjt16, xjct16);
    k_gemm<<<dim3(N_ / 64, B_), dim3(256), 0, stream>>>(Wg16, xt16, xjt16, xjct16, cbi, outp);
}

// Round 10
// 309.157 us; speedup vs baseline: 1.1739x; 1.0243x over previous
//
#include <hip/hip_runtime.h>
#include <hip/hip_bf16.h>
#include <math.h>

#define B_   4
#define C_   192
#define N_   6400
#define K_   9
#define M_   50
#define TK_  12
#define OC_  192
#define KC_  576     // 3*C
#define CH_  100     // 64-point chunks per batch
#define LSTR 53      // padded lg row stride (fp32; odd -> conflict-free)
#define TSTR 72      // lgT row stride (bf16)
#define XSTR 40      // xT / staging row stride (bf16), 80 B, 16B-aligned
#define GSTR 40      // k_gemm bf16 LDS row stride

typedef __bf16 b16x8 __attribute__((ext_vector_type(8)));
typedef float f32x4 __attribute__((ext_vector_type(4)));

__device__ inline unsigned short f2b(float f) {
    union { __hip_bfloat16 h; unsigned short u; } v;
    v.h = __float2bfloat16(f);
    return v.u;
}
__device__ inline float b2f(unsigned short u) {
    union { float f; unsigned int i; } v;
    v.i = ((unsigned int)u) << 16;
    return v.f;
}

// ---------------- W re-permute -> bf16: Wg16[o][t*192+ch] = conv_w[o][ch*3+t]
__global__ void k_rearrange_w(const float* __restrict__ cw, unsigned short* __restrict__ Wg16) {
    int g = blockIdx.x * 256 + threadIdx.x;           // < 192*576
    int o = g / KC_, r = g % KC_;
    int t = r / C_, ch = r % C_;
    Wg16[g] = f2b(cw[o * KC_ + ch * 3 + t]);
}

// -------- transpose x (b,c,n) -> xt fp32 + xt16 (bf16 hi) + xt16l (bf16 lo) --
__global__ void k_transpose(const float* __restrict__ x, float* __restrict__ xt,
                            unsigned short* __restrict__ xt16,
                            unsigned short* __restrict__ xt16l) {
    __shared__ float tile[32][33];
    int b = blockIdx.z;
    int p0 = blockIdx.x * 32, c0 = blockIdx.y * 32;
    int tx = threadIdx.x, ty = threadIdx.y;
    const float* xb = x + (size_t)b * C_ * N_;
    float* xtb = xt + (size_t)b * N_ * C_;
    unsigned short* xt16b = xt16 + (size_t)b * N_ * C_;
    unsigned short* xt16lb = xt16l + (size_t)b * N_ * C_;
#pragma unroll
    for (int i = 0; i < 4; i++) {
        int cc = ty + 8 * i;
        tile[cc][tx] = xb[(size_t)(c0 + cc) * N_ + p0 + tx];
    }
    __syncthreads();
#pragma unroll
    for (int i = 0; i < 4; i++) {
        int pp = ty + 8 * i;
        float v = tile[tx][pp];
        size_t o = (size_t)(p0 + pp) * C_ + c0 + tx;
        xtb[o] = v;
        unsigned short hi = f2b(v);
        xt16b[o] = hi;
        xt16lb[o] = f2b(v - b2f(hi));
    }
}

// -- initial centroids: 5x10 pool (+ |c|^2, + hi/lo split, zero pad rows) -----
__global__ __launch_bounds__(192) void k_init_cent(const float* __restrict__ xt,
        float* __restrict__ cent, float* __restrict__ c2,
        unsigned short* __restrict__ centh, unsigned short* __restrict__ centl) {
    int m = blockIdx.x, b = blockIdx.y, c = threadIdx.x;
    if (m >= M_) {   // zero-pad rows 50..63 of the split arrays
        size_t o = ((size_t)b * 64 + m) * C_ + c;
        centh[o] = 0; centl[o] = 0;
        return;
    }
    int gy = m / 10, gx = m % 10;
    const float* xtb = xt + (size_t)b * N_ * C_;
    float s = 0.f;
    for (int yy = 0; yy < 16; yy++)
        for (int xx = 0; xx < 8; xx++) {
            int p = (gy * 16 + yy) * 80 + gx * 8 + xx;
            s += xtb[(size_t)p * C_ + c];
        }
    float v = s * (1.f / 128.f);
    cent[((size_t)b * M_ + m) * C_ + c] = v;
    size_t oh = ((size_t)b * 64 + m) * C_ + c;
    unsigned short hi = f2b(v);
    centh[oh] = hi;
    centl[oh] = f2b(v - b2f(hi));
    float q = v * v;
    __shared__ float red[3];
#pragma unroll
    for (int off = 32; off > 0; off >>= 1) q += __shfl_down(q, off, 64);
    if ((c & 63) == 0) red[c >> 6] = q;
    __syncthreads();
    if (c == 0) c2[(size_t)b * M_ + m] = red[0] + red[1] + red[2];
}

// ==== fused: logits (MFMA-split fast path / fp32 exact path) + softmax +
//      bf16-split MFMA partials (+ topk on last iter) ========================
// LDS aliasing (51712 B):
//  phase1-fast:  chS,clS,xhS,xlS bf16 [64][40]  @ [0 .. 20480)
//  phase1-exact: Ac,Bp fp32 [16][68]            @ [0 .. 8704)
//  lg fp32 [64][LSTR]                           @ [20480 .. 34048)
//  phase2: lgTh,lgTl [64][72]                   @ [0 .. 18432)   (staging dead)
//          xTh,xTl   [208][40]                  @ [18432 .. 51712) (lg dead)
__global__ __launch_bounds__(256) void k_logits_upd(const float* __restrict__ xt,
        const unsigned short* __restrict__ xt16, const unsigned short* __restrict__ xt16l,
        const float* __restrict__ cent,
        const unsigned short* __restrict__ centh, const unsigned short* __restrict__ centl,
        const float* __restrict__ c2g,
        float* __restrict__ part, float* __restrict__ wsp,
        int* __restrict__ nn, int do_topk, int fast) {
    __shared__ alignas(16) char smem[51712];
    __shared__ float sred[256];
    unsigned short* chS = (unsigned short*)smem;          // [64][XSTR]
    unsigned short* clS = chS + 64 * XSTR;
    unsigned short* xhS = clS + 64 * XSTR;
    unsigned short* xlS = xhS + 64 * XSTR;
    float* Ac = (float*)smem;                             // fp32 path staging
    float* Bp = (float*)(smem + 4352);
    float* lg = (float*)(smem + 20480);
    unsigned short* lgTh = (unsigned short*)smem;
    unsigned short* lgTl = (unsigned short*)(smem + 9216);
    unsigned short* xTh = (unsigned short*)(smem + 18432);
    unsigned short* xTl = (unsigned short*)(smem + 35072);
    int b = blockIdx.y;
    int blk = blockIdx.x;
    int p0 = blk * 64;
    int tid = threadIdx.x;
    int tx = tid & 15, ty = tid >> 4;
    int lr = tid >> 2, lq = tid & 3;
    int wave = tid >> 6, lane = tid & 63;
    int m16 = lane & 15, q = lane >> 4;
    const float* xb = xt + ((size_t)b * N_ + p0) * C_;
    const unsigned short* x16b = xt16 + ((size_t)b * N_ + p0) * C_;
    const unsigned short* x16lb = xt16l + ((size_t)b * N_ + p0) * C_;
    if (fast) {
        // ---- phase 1 fast: split-bf16 MFMA logits (iters 0,1 only) ----
        const unsigned short* chg = centh + (size_t)b * 64 * C_;
        const unsigned short* clg = centl + (size_t)b * 64 * C_;
        f32x4 acc1[4];
#pragma unroll
        for (int i = 0; i < 4; i++) acc1[i] = (f32x4){0.f, 0.f, 0.f, 0.f};
        for (int kt = 0; kt < 6; kt++) {
            int kg = kt * 32;
            int row = tid >> 2, ko = (tid & 3) * 8;
            int4 cvh = *(const int4*)&chg[(size_t)row * C_ + kg + ko];
            int4 cvl = *(const int4*)&clg[(size_t)row * C_ + kg + ko];
            int4 xvh = *(const int4*)&x16b[(size_t)row * C_ + kg + ko];
            int4 xvl = *(const int4*)&x16lb[(size_t)row * C_ + kg + ko];
            __syncthreads();
            *(int4*)&chS[row * XSTR + ko] = cvh;
            *(int4*)&clS[row * XSTR + ko] = cvl;
            *(int4*)&xhS[row * XSTR + ko] = xvh;
            *(int4*)&xlS[row * XSTR + ko] = xvl;
            __syncthreads();
            b16x8 bh = *(const b16x8*)&xhS[(wave * 16 + m16) * XSTR + q * 8];
            b16x8 bl = *(const b16x8*)&xlS[(wave * 16 + m16) * XSTR + q * 8];
#pragma unroll
            for (int mt = 0; mt < 4; mt++) {
                b16x8 ah = *(const b16x8*)&chS[(mt * 16 + m16) * XSTR + q * 8];
                b16x8 al = *(const b16x8*)&clS[(mt * 16 + m16) * XSTR + q * 8];
                acc1[mt] = __builtin_amdgcn_mfma_f32_16x16x32_bf16(ah, bh, acc1[mt], 0, 0, 0);
                acc1[mt] = __builtin_amdgcn_mfma_f32_16x16x32_bf16(ah, bl, acc1[mt], 0, 0, 0);
                acc1[mt] = __builtin_amdgcn_mfma_f32_16x16x32_bf16(al, bh, acc1[mt], 0, 0, 0);
            }
        }
        __syncthreads();
        // D row m = mt*16+q*4+r, col p = wave*16+m16
#pragma unroll
        for (int mt = 0; mt < 4; mt++) {
#pragma unroll
            for (int r = 0; r < 4; r++) {
                int m = mt * 16 + q * 4 + r;
                if (m < M_) {
                    float c2v = c2g[(size_t)b * M_ + m];
                    lg[(wave * 16 + m16) * LSTR + m] = 2.f * acc1[mt][r] - c2v;
                }
            }
        }
    } else {
        // ---- phase 1 exact: fp32 VALU logits (iter 2 -> topk) ----
        const float* cb = cent + (size_t)b * M_ * C_;
        float acc[4][4];
#pragma unroll
        for (int i = 0; i < 4; i++)
#pragma unroll
            for (int j = 0; j < 4; j++) acc[i][j] = 0.f;
        for (int kt = 0; kt < 12; kt++) {
            int kg = kt * 16;
            float4 cv = make_float4(0.f, 0.f, 0.f, 0.f);
            if (lr < M_) cv = *(const float4*)&cb[(size_t)lr * C_ + kg + 4 * lq];
            float4 pv = *(const float4*)&xb[(size_t)lr * C_ + kg + 4 * lq];
            __syncthreads();
            Ac[(4 * lq + 0) * 68 + lr] = cv.x; Ac[(4 * lq + 1) * 68 + lr] = cv.y;
            Ac[(4 * lq + 2) * 68 + lr] = cv.z; Ac[(4 * lq + 3) * 68 + lr] = cv.w;
            Bp[(4 * lq + 0) * 68 + lr] = pv.x; Bp[(4 * lq + 1) * 68 + lr] = pv.y;
            Bp[(4 * lq + 2) * 68 + lr] = pv.z; Bp[(4 * lq + 3) * 68 + lr] = pv.w;
            __syncthreads();
#pragma unroll
            for (int kk = 0; kk < 16; kk++) {
                float4 a = *(const float4*)&Ac[kk * 68 + 4 * ty];
                float4 bb = *(const float4*)&Bp[kk * 68 + 4 * tx];
                acc[0][0] += a.x * bb.x; acc[0][1] += a.x * bb.y; acc[0][2] += a.x * bb.z; acc[0][3] += a.x * bb.w;
                acc[1][0] += a.y * bb.x; acc[1][1] += a.y * bb.y; acc[1][2] += a.y * bb.z; acc[1][3] += a.y * bb.w;
                acc[2][0] += a.z * bb.x; acc[2][1] += a.z * bb.y; acc[2][2] += a.z * bb.z; acc[2][3] += a.z * bb.w;
                acc[3][0] += a.w * bb.x; acc[3][1] += a.w * bb.y; acc[3][2] += a.w * bb.z; acc[3][3] += a.w * bb.w;
            }
        }
        __syncthreads();
#pragma unroll
        for (int i = 0; i < 4; i++) {
            int m = 4 * ty + i;
            if (m < M_) {
                float c2v = c2g[(size_t)b * M_ + m];
#pragma unroll
                for (int j = 0; j < 4; j++)
                    lg[(4 * tx + j) * LSTR + m] = 2.f * acc[i][j] - c2v;
            }
        }
    }
    __syncthreads();
    // ---- softmax (4-way parallel per row) ----
    {
        int p = tid & 63, prt = tid >> 6;
        int m0 = prt * 13;
        int m1 = (prt == 3) ? M_ : m0 + 13;
        float* row = &lg[p * LSTR];
        float mx = -1e30f;
        for (int m = m0; m < m1; m++) mx = fmaxf(mx, row[m]);
        sred[prt * 64 + p] = mx;
        __syncthreads();
        mx = fmaxf(fmaxf(sred[p], sred[64 + p]), fmaxf(sred[128 + p], sred[192 + p]));
        float s = 0.f;
        for (int m = m0; m < m1; m++) {
            float e = expf(row[m] - mx);
            row[m] = e;
            s += e;
        }
        __syncthreads();
        sred[prt * 64 + p] = s;
        __syncthreads();
        s = sred[p] + sred[64 + p] + sred[128 + p] + sred[192 + p];
        float inv = 1.f / s;
        for (int m = m0; m < m1; m++) row[m] *= inv;
    }
    __syncthreads();
    // ---- build lgT[m][p] hi/lo bf16 (m-major lanes: conflict-free both sides)
    for (int j = tid; j < 64 * 64; j += 256) {
        int m = j >> 6, p = j & 63;
        float w = (m < M_) ? lg[p * LSTR + m] : 0.f;
        unsigned short hi = f2b(w);
        lgTh[m * TSTR + p] = hi;
        lgTl[m * TSTR + p] = f2b(w - b2f(hi));
    }
    __syncthreads();
    // ---- topk on last iteration (reads+destroys lg; before xT overwrites) ---
    if (do_topk && tid < 64) {
        float* row = &lg[tid * LSTR];
        int* nb = nn + ((size_t)b * N_ + p0 + tid) * TK_;
        for (int r = 0; r < TK_; r++) {
            float bv = -1.f;
            int bi = 0;
            for (int m = 0; m < M_; m++) {
                float v = row[m];
                if (v > bv) { bv = v; bi = m; }   // strict > : lowest index wins ties
            }
            nb[r] = bi;
            row[bi] = -1.f;
        }
    }
    // ---- phase 2: part[m][c] = sum_p w*x via 3-term bf16-split MFMA ----
    f32x4 acc2[13];
#pragma unroll
    for (int i = 0; i < 13; i++) acc2[i] = (f32x4){0.f, 0.f, 0.f, 0.f};
    for (int h = 0; h < 2; h++) {
        __syncthreads();   // lg/topk done (h=0); prev MFMA reads done (h=1)
        for (int j = tid; j < 24 * 32; j += 256) {
            int pl = j / 24, ko = (j - pl * 24) * 8;
            int4 vh = *(const int4*)&x16b[(size_t)(h * 32 + pl) * C_ + ko];
            int4 vl = *(const int4*)&x16lb[(size_t)(h * 32 + pl) * C_ + ko];
            const unsigned short* ph = (const unsigned short*)&vh;
            const unsigned short* pv = (const unsigned short*)&vl;
#pragma unroll
            for (int i = 0; i < 8; i++) {
                xTh[(ko + i) * XSTR + pl] = ph[i];
                xTl[(ko + i) * XSTR + pl] = pv[i];
            }
        }
        for (int j = tid; j < 32 * 16; j += 256) {
            int pl = j & 31, c = C_ + (j >> 5);
            xTh[c * XSTR + pl] = (c == C_) ? f2b(1.f) : 0;
            xTl[c * XSTR + pl] = 0;
        }
        __syncthreads();
        b16x8 ah = *(const b16x8*)&lgTh[(wave * 16 + m16) * TSTR + h * 32 + q * 8];
        b16x8 al = *(const b16x8*)&lgTl[(wave * 16 + m16) * TSTR + h * 32 + q * 8];
#pragma unroll
        for (int ct = 0; ct < 13; ct++) {
            b16x8 bh = *(const b16x8*)&xTh[(ct * 16 + m16) * XSTR + q * 8];
            b16x8 bl = *(const b16x8*)&xTl[(ct * 16 + m16) * XSTR + q * 8];
            acc2[ct] = __builtin_amdgcn_mfma_f32_16x16x32_bf16(ah, bh, acc2[ct], 0, 0, 0);
            acc2[ct] = __builtin_amdgcn_mfma_f32_16x16x32_bf16(ah, bl, acc2[ct], 0, 0, 0);
            acc2[ct] = __builtin_amdgcn_mfma_f32_16x16x32_bf16(al, bh, acc2[ct], 0, 0, 0);
        }
    }
    // ---- epilogue: D row m = wave*16 + q*4 + r, col c = ct*16 + m16 ----
    float* pb = part + ((size_t)b * CH_ + blk) * (size_t)(M_ * C_);
    int mbase = wave * 16 + q * 4;
#pragma unroll
    for (int ct = 0; ct < 13; ct++) {
        int c = ct * 16 + m16;
#pragma unroll
        for (int r = 0; r < 4; r++) {
            int mm = mbase + r;
            if (mm >= M_) continue;
            float v = acc2[ct][r];
            if (c < C_) pb[(size_t)mm * C_ + c] = v;
            else if (c == C_) wsp[((size_t)b * CH_ + blk) * M_ + mm] = v;
        }
    }
}

__global__ __launch_bounds__(192) void k_upd_reduce(const float* __restrict__ part,
        const float* __restrict__ wsp, float* __restrict__ cent, float* __restrict__ c2,
        unsigned short* __restrict__ cent16,
        unsigned short* __restrict__ centh, unsigned short* __restrict__ centl, int last) {
    int m = blockIdx.x, b = blockIdx.y, c = threadIdx.x;
    __shared__ float sws;
    __shared__ float red[3];
    if (c == 0) {
        float s = 0.f;
        for (int ch = 0; ch < CH_; ch++) s += wsp[((size_t)b * CH_ + ch) * M_ + m];
        sws = s + 1e-8f;
    }
    float s = 0.f;
    for (int ch = 0; ch < CH_; ch++)
        s += part[(((size_t)b * CH_ + ch) * M_ + m) * (size_t)C_ + c];
    __syncthreads();
    float v = s / sws;
    size_t o = ((size_t)b * M_ + m) * C_ + c;
    cent[o] = v;
    if (last) cent16[o] = f2b(v);
    size_t oh = ((size_t)b * 64 + m) * C_ + c;
    unsigned short hi = f2b(v);
    centh[oh] = hi;
    centl[oh] = f2b(v - b2f(hi));
    float q = v * v;
#pragma unroll
    for (int off = 32; off > 0; off >>= 1) q += __shfl_down(q, off, 64);
    if ((c & 63) == 0) red[c >> 6] = q;
    __syncthreads();
    if (c == 0) c2[(size_t)b * M_ + m] = red[0] + red[1] + red[2];
}

// ---------------- gathers (bf16 sources): edge max-rel + topk-centroid max ---
__global__ __launch_bounds__(192) void k_gather(const unsigned short* __restrict__ xt16,
        const unsigned short* __restrict__ cent16, const int* __restrict__ edge,
        const int* __restrict__ nn, unsigned short* __restrict__ xjt16,
        unsigned short* __restrict__ xjct16) {
    __shared__ int sidx[2 * K_ + TK_];
    int p = blockIdx.x, b = blockIdx.y, c = threadIdx.x;
    if (c < K_)
        sidx[c] = edge[((size_t)b * N_ + p) * K_ + c];
    else if (c < 2 * K_)
        sidx[c] = edge[(size_t)B_ * N_ * K_ + ((size_t)b * N_ + p) * K_ + (c - K_)];
    else if (c < 2 * K_ + TK_)
        sidx[c] = nn[((size_t)b * N_ + p) * TK_ + (c - 2 * K_)];
    __syncthreads();
    const unsigned short* xb = xt16 + (size_t)b * N_ * C_;
    const unsigned short* cbv = cent16 + (size_t)b * M_ * C_;
    float xv = b2f(xb[(size_t)p * C_ + c]);
    float mj = -1e30f;
#pragma unroll
    for (int kk = 0; kk < K_; kk++) {
        float vj = b2f(xb[(size_t)sidx[kk] * C_ + c]);
        float vi = b2f(xb[(size_t)sidx[K_ + kk] * C_ + c]);
        mj = fmaxf(mj, vj - vi);
    }
    float mc = -1e30f;
#pragma unroll
    for (int kk = 0; kk < TK_; kk++)
        mc = fmaxf(mc, b2f(cbv[(size_t)sidx[2 * K_ + kk] * C_ + c]));
    size_t o = ((size_t)b * N_ + p) * C_ + c;
    xjt16[o] = f2b(mj);
    xjct16[o] = f2b(mc - xv);
}

// ------- final conv via bf16 MFMA: full-OC 192(o) x 64(p) tile, feat read once
__global__ __launch_bounds__(256) void k_gemm(const unsigned short* __restrict__ Wg16,
        const unsigned short* __restrict__ xt16, const unsigned short* __restrict__ xjt16,
        const unsigned short* __restrict__ xjct16, const float* __restrict__ bias,
        float* __restrict__ out) {
    __shared__ short As[192 * GSTR];   // Wg k-chunk [o][32k]
    __shared__ short Bs[64 * GSTR];    // feat k-chunk [p][32k]
    int b = blockIdx.y;
    int po = blockIdx.x * 64;
    int tid = threadIdx.x;
    int wave = tid >> 6, lane = tid & 63;
    int m16 = lane & 15, q = lane >> 4;
    const unsigned short* s0 = xt16 + (size_t)b * N_ * C_;
    const unsigned short* s1 = xjt16 + (size_t)b * N_ * C_;
    const unsigned short* s2 = xjct16 + (size_t)b * N_ * C_;
    f32x4 acc[12];
#pragma unroll
    for (int i = 0; i < 12; i++) acc[i] = (f32x4){0.f, 0.f, 0.f, 0.f};
    int brow = tid >> 2, bch = tid & 3;
    for (int kt = 0; kt < 18; kt++) {
        int kg = kt * 32;
        int prt = kg / C_, koff = kg - prt * C_;
        const unsigned short* src = (prt == 0) ? s0 : ((prt == 1) ? s1 : s2);
        int4 av[3];
#pragma unroll
        for (int t = 0; t < 3; t++) {
            int idx = t * 256 + tid;
            av[t] = *(const int4*)&Wg16[(size_t)(idx >> 2) * KC_ + kg + (idx & 3) * 8];
        }
        int4 bv = *(const int4*)&src[(size_t)(po + brow) * C_ + koff + bch * 8];
        __syncthreads();
#pragma unroll
        for (int t = 0; t < 3; t++) {
            int idx = t * 256 + tid;
            *(int4*)&As[(idx >> 2) * GSTR + (idx & 3) * 8] = av[t];
        }
        *(int4*)&Bs[brow * GSTR + bch * 8] = bv;
        __syncthreads();
        b16x8 bf = *(const b16x8*)&Bs[(wave * 16 + m16) * GSTR + q * 8];
#pragma unroll
        for (int of = 0; of < 12; of++) {
            b16x8 af = *(const b16x8*)&As[(of * 16 + m16) * GSTR + q * 8];
            acc[of] = __builtin_amdgcn_mfma_f32_16x16x32_bf16(af, bf, acc[of], 0, 0, 0);
        }
    }
    int p = po + wave * 16 + m16;
#pragma unroll
    for (int of = 0; of < 12; of++) {
        int o = of * 16 + q * 4;
        float4 bv = *(const float4*)&bias[o];
        float bia[4] = {bv.x, bv.y, bv.z, bv.w};
#pragma unroll
        for (int r = 0; r < 4; r++)
            out[((size_t)b * OC_ + o + r) * N_ + p] = fmaxf(acc[of][r] + bia[r], 0.f);
    }
}

extern "C" void kernel_launch(void* const* d_in, const int* in_sizes, int n_in,
                              void* d_out, int out_size, void* d_ws, size_t ws_size,
                              hipStream_t stream) {
    (void)in_sizes; (void)n_in; (void)out_size; (void)ws_size;
    const float* x   = (const float*)d_in[0];
    const int* edge  = (const int*)d_in[1];
    const float* cw  = (const float*)d_in[2];
    const float* cbi = (const float*)d_in[3];
    float* ws = (float*)d_ws;
    size_t o = 0;
    float* xt   = ws + o; o += (size_t)B_ * N_ * C_;
    unsigned short* xt16 = (unsigned short*)(ws + o); o += (size_t)B_ * N_ * C_ / 2;
    unsigned short* xt16l = (unsigned short*)(ws + o); o += (size_t)B_ * N_ * C_ / 2;
    unsigned short* Wg16 = (unsigned short*)(ws + o); o += (size_t)OC_ * KC_ / 2;
    float* cent = ws + o; o += (size_t)B_ * M_ * C_;
    unsigned short* cent16 = (unsigned short*)(ws + o); o += (size_t)B_ * M_ * C_ / 2;
    unsigned short* centh = (unsigned short*)(ws + o); o += (size_t)B_ * 64 * C_ / 2;
    unsigned short* centl = (unsigned short*)(ws + o); o += (size_t)B_ * 64 * C_ / 2;
    float* c2   = ws + o; o += (size_t)B_ * M_;
    float* part = ws + o; o += (size_t)B_ * CH_ * M_ * C_;
    float* wsp  = ws + o; o += (size_t)B_ * CH_ * M_;
    int* nn = (int*)(ws + o); o += (size_t)B_ * N_ * TK_;
    unsigned short* xjt16  = (unsigned short*)(ws + o); o += (size_t)B_ * N_ * C_ / 2;
    unsigned short* xjct16 = (unsigned short*)(ws + o); o += (size_t)B_ * N_ * C_ / 2;
    float* outp = (float*)d_out;

    k_rearrange_w<<<dim3(432), dim3(256), 0, stream>>>(cw, Wg16);
    k_transpose<<<dim3(N_ / 32, C_ / 32, B_), dim3(32, 8), 0, stream>>>(x, xt, xt16, xt16l);
    k_init_cent<<<dim3(64, B_), dim3(192), 0, stream>>>(xt, cent, c2, centh, centl);
    for (int it = 0; it < 3; it++) {
        k_logits_upd<<<dim3(CH_, B_), dim3(256), 0, stream>>>(xt, xt16, xt16l, cent,
            centh, centl, c2, part, wsp, nn, (it == 2) ? 1 : 0, (it < 2) ? 1 : 0);
        k_upd_reduce<<<dim3(M_, B_), dim3(192), 0, stream>>>(part, wsp, cent, c2,
            cent16, centh, centl, (it == 2) ? 1 : 0);
    }
    k_gather<<<dim3(N_, B_), dim3(192), 0, stream>>>(xt16, cent16, edge, nn, xjt16, xjct16);
    k_gemm<<<dim3(N_ / 64, B_), dim3(256), 0, stream>>>(Wg16, xt16, xjt16, xjct16, cbi, outp);
}

// Round 11
// 293.790 us; speedup vs baseline: 1.2352x; 1.0523x over previous
//
#include <hip/hip_runtime.h>
#include <hip/hip_bf16.h>
#include <math.h>

#define B_   4
#define C_   192
#define N_   6400
#define K_   9
#define M_   50
#define TK_  12
#define OC_  192
#define KC_  576     // 3*C
#define CH_  100     // 64-point chunks per batch
#define LSTR 53      // padded lg row stride (fp32; odd -> conflict-free)
#define TSTR 72      // lgT row stride (bf16)
#define XSTR 40      // xT row stride (bf16), 80 B, 16B-aligned
#define GSTR 40      // k_gemm bf16 LDS row stride

typedef __bf16 b16x8 __attribute__((ext_vector_type(8)));
typedef float f32x4 __attribute__((ext_vector_type(4)));

__device__ inline unsigned short f2b(float f) {
    union { __hip_bfloat16 h; unsigned short u; } v;
    v.h = __float2bfloat16(f);
    return v.u;
}
__device__ inline float b2f(unsigned short u) {
    union { float f; unsigned int i; } v;
    v.i = ((unsigned int)u) << 16;
    return v.f;
}

// ---------------- W re-permute -> bf16: Wg16[o][t*192+ch] = conv_w[o][ch*3+t]
__global__ void k_rearrange_w(const float* __restrict__ cw, unsigned short* __restrict__ Wg16) {
    int g = blockIdx.x * 256 + threadIdx.x;           // < 192*576
    int o = g / KC_, r = g % KC_;
    int t = r / C_, ch = r % C_;
    Wg16[g] = f2b(cw[o * KC_ + ch * 3 + t]);
}

// -------- transpose x (b,c,n) -> xt fp32 + xt16 (bf16 hi) + xt16l (bf16 lo) --
__global__ void k_transpose(const float* __restrict__ x, float* __restrict__ xt,
                            unsigned short* __restrict__ xt16,
                            unsigned short* __restrict__ xt16l) {
    __shared__ float tile[32][33];
    int b = blockIdx.z;
    int p0 = blockIdx.x * 32, c0 = blockIdx.y * 32;
    int tx = threadIdx.x, ty = threadIdx.y;
    const float* xb = x + (size_t)b * C_ * N_;
    float* xtb = xt + (size_t)b * N_ * C_;
    unsigned short* xt16b = xt16 + (size_t)b * N_ * C_;
    unsigned short* xt16lb = xt16l + (size_t)b * N_ * C_;
#pragma unroll
    for (int i = 0; i < 4; i++) {
        int cc = ty + 8 * i;
        tile[cc][tx] = xb[(size_t)(c0 + cc) * N_ + p0 + tx];
    }
    __syncthreads();
#pragma unroll
    for (int i = 0; i < 4; i++) {
        int pp = ty + 8 * i;
        float v = tile[tx][pp];
        size_t o = (size_t)(p0 + pp) * C_ + c0 + tx;
        xtb[o] = v;
        unsigned short hi = f2b(v);
        xt16b[o] = hi;
        xt16lb[o] = f2b(v - b2f(hi));
    }
}

// -- initial centroids: 5x10 pool (+ |c|^2, + hi/lo split, zero pad rows) -----
__global__ __launch_bounds__(192) void k_init_cent(const float* __restrict__ xt,
        float* __restrict__ cent, float* __restrict__ c2,
        unsigned short* __restrict__ centh, unsigned short* __restrict__ centl) {
    int m = blockIdx.x, b = blockIdx.y, c = threadIdx.x;
    if (m >= M_) {   // zero-pad rows 50..63 of the split arrays
        size_t o = ((size_t)b * 64 + m) * C_ + c;
        centh[o] = 0; centl[o] = 0;
        return;
    }
    int gy = m / 10, gx = m % 10;
    const float* xtb = xt + (size_t)b * N_ * C_;
    float s = 0.f;
    for (int yy = 0; yy < 16; yy++)
        for (int xx = 0; xx < 8; xx++) {
            int p = (gy * 16 + yy) * 80 + gx * 8 + xx;
            s += xtb[(size_t)p * C_ + c];
        }
    float v = s * (1.f / 128.f);
    cent[((size_t)b * M_ + m) * C_ + c] = v;
    size_t oh = ((size_t)b * 64 + m) * C_ + c;
    unsigned short hi = f2b(v);
    centh[oh] = hi;
    centl[oh] = f2b(v - b2f(hi));
    float q = v * v;
    __shared__ float red[3];
#pragma unroll
    for (int off = 32; off > 0; off >>= 1) q += __shfl_down(q, off, 64);
    if ((c & 63) == 0) red[c >> 6] = q;
    __syncthreads();
    if (c == 0) c2[(size_t)b * M_ + m] = red[0] + red[1] + red[2];
}

// ==== fused: logits (direct-global MFMA fast path / fp32 exact path) +
//      softmax + bf16-split MFMA partials (+ topk on last iter) ==============
// LDS aliasing (51712 B):
//  phase1-exact: Ac,Bp fp32 [16][68]            @ [0 .. 8704)
//  lg fp32 [64][LSTR]                           @ [20480 .. 34048)
//  phase2: lgTh,lgTl [64][72]                   @ [0 .. 18432)   (staging dead)
//          xTh,xTl   [208][40]                  @ [18432 .. 51712) (lg dead)
__global__ __launch_bounds__(256) void k_logits_upd(const float* __restrict__ xt,
        const unsigned short* __restrict__ xt16, const unsigned short* __restrict__ xt16l,
        const float* __restrict__ cent,
        const unsigned short* __restrict__ centh, const unsigned short* __restrict__ centl,
        const float* __restrict__ c2g,
        float* __restrict__ part, float* __restrict__ wsp,
        int* __restrict__ nn, int do_topk, int fast) {
    __shared__ alignas(16) char smem[51712];
    __shared__ float sred[256];
    float* Ac = (float*)smem;                             // fp32 path staging
    float* Bp = (float*)(smem + 4352);
    float* lg = (float*)(smem + 20480);
    unsigned short* lgTh = (unsigned short*)smem;
    unsigned short* lgTl = (unsigned short*)(smem + 9216);
    unsigned short* xTh = (unsigned short*)(smem + 18432);
    unsigned short* xTl = (unsigned short*)(smem + 35072);
    int b = blockIdx.y;
    int blk = blockIdx.x;
    int p0 = blk * 64;
    int tid = threadIdx.x;
    int tx = tid & 15, ty = tid >> 4;
    int lr = tid >> 2, lq = tid & 3;
    int wave = tid >> 6, lane = tid & 63;
    int m16 = lane & 15, q = lane >> 4;
    const float* xb = xt + ((size_t)b * N_ + p0) * C_;
    const unsigned short* x16b = xt16 + ((size_t)b * N_ + p0) * C_;
    const unsigned short* x16lb = xt16l + ((size_t)b * N_ + p0) * C_;
    if (fast) {
        // ---- phase 1 fast: split-bf16 MFMA logits, fragments direct from
        //      global (xt16/centh already in [row][k] fragment layout) ----
        const unsigned short* chg = centh + (size_t)b * 64 * C_;
        const unsigned short* clg = centl + (size_t)b * 64 * C_;
        f32x4 acc1[4];
#pragma unroll
        for (int i = 0; i < 4; i++) acc1[i] = (f32x4){0.f, 0.f, 0.f, 0.f};
#pragma unroll
        for (int kt = 0; kt < 6; kt++) {
            int kg = kt * 32;
            size_t xo = (size_t)(wave * 16 + m16) * C_ + kg + q * 8;
            b16x8 bh = *(const b16x8*)&x16b[xo];
            b16x8 bl = *(const b16x8*)&x16lb[xo];
#pragma unroll
            for (int mt = 0; mt < 4; mt++) {
                size_t co = (size_t)(mt * 16 + m16) * C_ + kg + q * 8;
                b16x8 ah = *(const b16x8*)&chg[co];
                b16x8 al = *(const b16x8*)&clg[co];
                acc1[mt] = __builtin_amdgcn_mfma_f32_16x16x32_bf16(ah, bh, acc1[mt], 0, 0, 0);
                acc1[mt] = __builtin_amdgcn_mfma_f32_16x16x32_bf16(ah, bl, acc1[mt], 0, 0, 0);
                acc1[mt] = __builtin_amdgcn_mfma_f32_16x16x32_bf16(al, bh, acc1[mt], 0, 0, 0);
            }
        }
        // D row m = mt*16+q*4+r, col p = wave*16+m16
#pragma unroll
        for (int mt = 0; mt < 4; mt++) {
#pragma unroll
            for (int r = 0; r < 4; r++) {
                int m = mt * 16 + q * 4 + r;
                if (m < M_) {
                    float c2v = c2g[(size_t)b * M_ + m];
                    lg[(wave * 16 + m16) * LSTR + m] = 2.f * acc1[mt][r] - c2v;
                }
            }
        }
    } else {
        // ---- phase 1 exact: fp32 VALU logits (iter 2 -> topk) ----
        const float* cb = cent + (size_t)b * M_ * C_;
        float acc[4][4];
#pragma unroll
        for (int i = 0; i < 4; i++)
#pragma unroll
            for (int j = 0; j < 4; j++) acc[i][j] = 0.f;
        for (int kt = 0; kt < 12; kt++) {
            int kg = kt * 16;
            float4 cv = make_float4(0.f, 0.f, 0.f, 0.f);
            if (lr < M_) cv = *(const float4*)&cb[(size_t)lr * C_ + kg + 4 * lq];
            float4 pv = *(const float4*)&xb[(size_t)lr * C_ + kg + 4 * lq];
            __syncthreads();
            Ac[(4 * lq + 0) * 68 + lr] = cv.x; Ac[(4 * lq + 1) * 68 + lr] = cv.y;
            Ac[(4 * lq + 2) * 68 + lr] = cv.z; Ac[(4 * lq + 3) * 68 + lr] = cv.w;
            Bp[(4 * lq + 0) * 68 + lr] = pv.x; Bp[(4 * lq + 1) * 68 + lr] = pv.y;
            Bp[(4 * lq + 2) * 68 + lr] = pv.z; Bp[(4 * lq + 3) * 68 + lr] = pv.w;
            __syncthreads();
#pragma unroll
            for (int kk = 0; kk < 16; kk++) {
                float4 a = *(const float4*)&Ac[kk * 68 + 4 * ty];
                float4 bb = *(const float4*)&Bp[kk * 68 + 4 * tx];
                acc[0][0] += a.x * bb.x; acc[0][1] += a.x * bb.y; acc[0][2] += a.x * bb.z; acc[0][3] += a.x * bb.w;
                acc[1][0] += a.y * bb.x; acc[1][1] += a.y * bb.y; acc[1][2] += a.y * bb.z; acc[1][3] += a.y * bb.w;
                acc[2][0] += a.z * bb.x; acc[2][1] += a.z * bb.y; acc[2][2] += a.z * bb.z; acc[2][3] += a.z * bb.w;
                acc[3][0] += a.w * bb.x; acc[3][1] += a.w * bb.y; acc[3][2] += a.w * bb.z; acc[3][3] += a.w * bb.w;
            }
        }
        __syncthreads();
#pragma unroll
        for (int i = 0; i < 4; i++) {
            int m = 4 * ty + i;
            if (m < M_) {
                float c2v = c2g[(size_t)b * M_ + m];
#pragma unroll
                for (int j = 0; j < 4; j++)
                    lg[(4 * tx + j) * LSTR + m] = 2.f * acc[i][j] - c2v;
            }
        }
    }
    __syncthreads();
    // ---- softmax (4-way parallel per row) ----
    {
        int p = tid & 63, prt = tid >> 6;
        int m0 = prt * 13;
        int m1 = (prt == 3) ? M_ : m0 + 13;
        float* row = &lg[p * LSTR];
        float mx = -1e30f;
        for (int m = m0; m < m1; m++) mx = fmaxf(mx, row[m]);
        sred[prt * 64 + p] = mx;
        __syncthreads();
        mx = fmaxf(fmaxf(sred[p], sred[64 + p]), fmaxf(sred[128 + p], sred[192 + p]));
        float s = 0.f;
        for (int m = m0; m < m1; m++) {
            float e = expf(row[m] - mx);
            row[m] = e;
            s += e;
        }
        __syncthreads();
        sred[prt * 64 + p] = s;
        __syncthreads();
        s = sred[p] + sred[64 + p] + sred[128 + p] + sred[192 + p];
        float inv = 1.f / s;
        for (int m = m0; m < m1; m++) row[m] *= inv;
    }
    __syncthreads();
    // ---- build lgT[m][p] hi/lo bf16 (lane-consecutive p: conflict-free) ----
    for (int j = tid; j < 64 * 64; j += 256) {
        int m = j >> 6, p = j & 63;
        float w = (m < M_) ? lg[p * LSTR + m] : 0.f;
        unsigned short hi = f2b(w);
        lgTh[m * TSTR + p] = hi;
        lgTl[m * TSTR + p] = f2b(w - b2f(hi));
    }
    __syncthreads();
    // ---- topk on last iteration (reads+destroys lg; before xT overwrites) ---
    if (do_topk && tid < 64) {
        float* row = &lg[tid * LSTR];
        int* nb = nn + ((size_t)b * N_ + p0 + tid) * TK_;
        for (int r = 0; r < TK_; r++) {
            float bv = -1.f;
            int bi = 0;
            for (int m = 0; m < M_; m++) {
                float v = row[m];
                if (v > bv) { bv = v; bi = m; }   // strict > : lowest index wins ties
            }
            nb[r] = bi;
            row[bi] = -1.f;
        }
    }
    // ---- phase 2: part[m][c] = sum_p w*x via 3-term bf16-split MFMA ----
    f32x4 acc2[13];
#pragma unroll
    for (int i = 0; i < 13; i++) acc2[i] = (f32x4){0.f, 0.f, 0.f, 0.f};
    for (int h = 0; h < 2; h++) {
        __syncthreads();   // lg/topk done (h=0); prev MFMA reads done (h=1)
        // xT build: lanes consecutive pl -> contiguous b16 writes (no conflict)
        for (int j = tid; j < 32 * 24; j += 256) {
            int pl = j & 31, ko = (j >> 5) * 8;
            int4 vh = *(const int4*)&x16b[(size_t)(h * 32 + pl) * C_ + ko];
            int4 vl = *(const int4*)&x16lb[(size_t)(h * 32 + pl) * C_ + ko];
            const unsigned short* ph = (const unsigned short*)&vh;
            const unsigned short* pv = (const unsigned short*)&vl;
#pragma unroll
            for (int i = 0; i < 8; i++) {
                xTh[(ko + i) * XSTR + pl] = ph[i];
                xTl[(ko + i) * XSTR + pl] = pv[i];
            }
        }
        for (int j = tid; j < 32 * 16; j += 256) {
            int pl = j & 31, c = C_ + (j >> 5);
            xTh[c * XSTR + pl] = (c == C_) ? f2b(1.f) : 0;
            xTl[c * XSTR + pl] = 0;
        }
        __syncthreads();
        b16x8 ah = *(const b16x8*)&lgTh[(wave * 16 + m16) * TSTR + h * 32 + q * 8];
        b16x8 al = *(const b16x8*)&lgTl[(wave * 16 + m16) * TSTR + h * 32 + q * 8];
#pragma unroll
        for (int ct = 0; ct < 13; ct++) {
            b16x8 bh = *(const b16x8*)&xTh[(ct * 16 + m16) * XSTR + q * 8];
            b16x8 bl = *(const b16x8*)&xTl[(ct * 16 + m16) * XSTR + q * 8];
            acc2[ct] = __builtin_amdgcn_mfma_f32_16x16x32_bf16(ah, bh, acc2[ct], 0, 0, 0);
            acc2[ct] = __builtin_amdgcn_mfma_f32_16x16x32_bf16(ah, bl, acc2[ct], 0, 0, 0);
            acc2[ct] = __builtin_amdgcn_mfma_f32_16x16x32_bf16(al, bh, acc2[ct], 0, 0, 0);
        }
    }
    // ---- epilogue: D row m = wave*16 + q*4 + r, col c = ct*16 + m16 ----
    float* pb = part + ((size_t)b * CH_ + blk) * (size_t)(M_ * C_);
    int mbase = wave * 16 + q * 4;
#pragma unroll
    for (int ct = 0; ct < 13; ct++) {
        int c = ct * 16 + m16;
#pragma unroll
        for (int r = 0; r < 4; r++) {
            int mm = mbase + r;
            if (mm >= M_) continue;
            float v = acc2[ct][r];
            if (c < C_) pb[(size_t)mm * C_ + c] = v;
            else if (c == C_) wsp[((size_t)b * CH_ + blk) * M_ + mm] = v;
        }
    }
}

__global__ __launch_bounds__(192) void k_upd_reduce(const float* __restrict__ part,
        const float* __restrict__ wsp, float* __restrict__ cent, float* __restrict__ c2,
        unsigned short* __restrict__ cent16,
        unsigned short* __restrict__ centh, unsigned short* __restrict__ centl, int last) {
    int m = blockIdx.x, b = blockIdx.y, c = threadIdx.x;
    __shared__ float sws;
    __shared__ float red[3];
    if (c == 0) {
        float s = 0.f;
        for (int ch = 0; ch < CH_; ch++) s += wsp[((size_t)b * CH_ + ch) * M_ + m];
        sws = s + 1e-8f;
    }
    float s = 0.f;
    for (int ch = 0; ch < CH_; ch++)
        s += part[(((size_t)b * CH_ + ch) * M_ + m) * (size_t)C_ + c];
    __syncthreads();
    float v = s / sws;
    size_t o = ((size_t)b * M_ + m) * C_ + c;
    cent[o] = v;
    if (last) cent16[o] = f2b(v);
    size_t oh = ((size_t)b * 64 + m) * C_ + c;
    unsigned short hi = f2b(v);
    centh[oh] = hi;
    centl[oh] = f2b(v - b2f(hi));
    float q = v * v;
#pragma unroll
    for (int off = 32; off > 0; off >>= 1) q += __shfl_down(q, off, 64);
    if ((c & 63) == 0) red[c >> 6] = q;
    __syncthreads();
    if (c == 0) c2[(size_t)b * M_ + m] = red[0] + red[1] + red[2];
}

// ---------------- gathers (bf16 sources): edge max-rel + topk-centroid max ---
__global__ __launch_bounds__(192) void k_gather(const unsigned short* __restrict__ xt16,
        const unsigned short* __restrict__ cent16, const int* __restrict__ edge,
        const int* __restrict__ nn, unsigned short* __restrict__ xjt16,
        unsigned short* __restrict__ xjct16) {
    __shared__ int sidx[2 * K_ + TK_];
    int p = blockIdx.x, b = blockIdx.y, c = threadIdx.x;
    if (c < K_)
        sidx[c] = edge[((size_t)b * N_ + p) * K_ + c];
    else if (c < 2 * K_)
        sidx[c] = edge[(size_t)B_ * N_ * K_ + ((size_t)b * N_ + p) * K_ + (c - K_)];
    else if (c < 2 * K_ + TK_)
        sidx[c] = nn[((size_t)b * N_ + p) * TK_ + (c - 2 * K_)];
    __syncthreads();
    const unsigned short* xb = xt16 + (size_t)b * N_ * C_;
    const unsigned short* cbv = cent16 + (size_t)b * M_ * C_;
    float xv = b2f(xb[(size_t)p * C_ + c]);
    float mj = -1e30f;
#pragma unroll
    for (int kk = 0; kk < K_; kk++) {
        float vj = b2f(xb[(size_t)sidx[kk] * C_ + c]);
        float vi = b2f(xb[(size_t)sidx[K_ + kk] * C_ + c]);
        mj = fmaxf(mj, vj - vi);
    }
    float mc = -1e30f;
#pragma unroll
    for (int kk = 0; kk < TK_; kk++)
        mc = fmaxf(mc, b2f(cbv[(size_t)sidx[2 * K_ + kk] * C_ + c]));
    size_t o = ((size_t)b * N_ + p) * C_ + c;
    xjt16[o] = f2b(mj);
    xjct16[o] = f2b(mc - xv);
}

// ------- final conv via bf16 MFMA: full-OC 192(o) x 64(p) tile, feat read once
__global__ __launch_bounds__(256) void k_gemm(const unsigned short* __restrict__ Wg16,
        const unsigned short* __restrict__ xt16, const unsigned short* __restrict__ xjt16,
        const unsigned short* __restrict__ xjct16, const float* __restrict__ bias,
        float* __restrict__ out) {
    __shared__ short As[192 * GSTR];   // Wg k-chunk [o][32k]
    __shared__ short Bs[64 * GSTR];    // feat k-chunk [p][32k]
    int b = blockIdx.y;
    int po = blockIdx.x * 64;
    int tid = threadIdx.x;
    int wave = tid >> 6, lane = tid & 63;
    int m16 = lane & 15, q = lane >> 4;
    const unsigned short* s0 = xt16 + (size_t)b * N_ * C_;
    const unsigned short* s1 = xjt16 + (size_t)b * N_ * C_;
    const unsigned short* s2 = xjct16 + (size_t)b * N_ * C_;
    f32x4 acc[12];
#pragma unroll
    for (int i = 0; i < 12; i++) acc[i] = (f32x4){0.f, 0.f, 0.f, 0.f};
    int brow = tid >> 2, bch = tid & 3;
    for (int kt = 0; kt < 18; kt++) {
        int kg = kt * 32;
        int prt = kg / C_, koff = kg - prt * C_;
        const unsigned short* src = (prt == 0) ? s0 : ((prt == 1) ? s1 : s2);
        int4 av[3];
#pragma unroll
        for (int t = 0; t < 3; t++) {
            int idx = t * 256 + tid;
            av[t] = *(const int4*)&Wg16[(size_t)(idx >> 2) * KC_ + kg + (idx & 3) * 8];
        }
        int4 bv = *(const int4*)&src[(size_t)(po + brow) * C_ + koff + bch * 8];
        __syncthreads();
#pragma unroll
        for (int t = 0; t < 3; t++) {
            int idx = t * 256 + tid;
            *(int4*)&As[(idx >> 2) * GSTR + (idx & 3) * 8] = av[t];
        }
        *(int4*)&Bs[brow * GSTR + bch * 8] = bv;
        __syncthreads();
        b16x8 bf = *(const b16x8*)&Bs[(wave * 16 + m16) * GSTR + q * 8];
#pragma unroll
        for (int of = 0; of < 12; of++) {
            b16x8 af = *(const b16x8*)&As[(of * 16 + m16) * GSTR + q * 8];
            acc[of] = __builtin_amdgcn_mfma_f32_16x16x32_bf16(af, bf, acc[of], 0, 0, 0);
        }
    }
    int p = po + wave * 16 + m16;
#pragma unroll
    for (int of = 0; of < 12; of++) {
        int o = of * 16 + q * 4;
        float4 bv = *(const float4*)&bias[o];
        float bia[4] = {bv.x, bv.y, bv.z, bv.w};
#pragma unroll
        for (int r = 0; r < 4; r++)
            out[((size_t)b * OC_ + o + r) * N_ + p] = fmaxf(acc[of][r] + bia[r], 0.f);
    }
}

extern "C" void kernel_launch(void* const* d_in, const int* in_sizes, int n_in,
                              void* d_out, int out_size, void* d_ws, size_t ws_size,
                              hipStream_t stream) {
    (void)in_sizes; (void)n_in; (void)out_size; (void)ws_size;
    const float* x   = (const float*)d_in[0];
    const int* edge  = (const int*)d_in[1];
    const float* cw  = (const float*)d_in[2];
    const float* cbi = (const float*)d_in[3];
    float* ws = (float*)d_ws;
    size_t o = 0;
    float* xt   = ws + o; o += (size_t)B_ * N_ * C_;
    unsigned short* xt16 = (unsigned short*)(ws + o); o += (size_t)B_ * N_ * C_ / 2;
    unsigned short* xt16l = (unsigned short*)(ws + o); o += (size_t)B_ * N_ * C_ / 2;
    unsigned short* Wg16 = (unsigned short*)(ws + o); o += (size_t)OC_ * KC_ / 2;
    float* cent = ws + o; o += (size_t)B_ * M_ * C_;
    unsigned short* cent16 = (unsigned short*)(ws + o); o += (size_t)B_ * M_ * C_ / 2;
    unsigned short* centh = (unsigned short*)(ws + o); o += (size_t)B_ * 64 * C_ / 2;
    unsigned short* centl = (unsigned short*)(ws + o); o += (size_t)B_ * 64 * C_ / 2;
    float* c2   = ws + o; o += (size_t)B_ * M_;
    float* part = ws + o; o += (size_t)B_ * CH_ * M_ * C_;
    float* wsp  = ws + o; o += (size_t)B_ * CH_ * M_;
    int* nn = (int*)(ws + o); o += (size_t)B_ * N_ * TK_;
    unsigned short* xjt16  = (unsigned short*)(ws + o); o += (size_t)B_ * N_ * C_ / 2;
    unsigned short* xjct16 = (unsigned short*)(ws + o); o += (size_t)B_ * N_ * C_ / 2;
    float* outp = (float*)d_out;

    k_rearrange_w<<<dim3(432), dim3(256), 0, stream>>>(cw, Wg16);
    k_transpose<<<dim3(N_ / 32, C_ / 32, B_), dim3(32, 8), 0, stream>>>(x, xt, xt16, xt16l);
    k_init_cent<<<dim3(64, B_), dim3(192), 0, stream>>>(xt, cent, c2, centh, centl);
    for (int it = 0; it < 3; it++) {
        k_logits_upd<<<dim3(CH_, B_), dim3(256), 0, stream>>>(xt, xt16, xt16l, cent,
            centh, centl, c2, part, wsp, nn, (it == 2) ? 1 : 0, (it < 2) ? 1 : 0);
        k_upd_reduce<<<dim3(M_, B_), dim3(192), 0, stream>>>(part, wsp, cent, c2,
            cent16, centh, centl, (it == 2) ? 1 : 0);
    }
    k_gather<<<dim3(N_, B_), dim3(192), 0, stream>>>(xt16, cent16, edge, nn, xjt16, xjct16);
    k_gemm<<<dim3(N_ / 64, B_), dim3(256), 0, stream>>>(Wg16, xt16, xjt16, xjct16, cbi, outp);
}